// Round 1
// baseline (778.856 us; speedup 1.0000x reference)
//
#include <hip/hip_runtime.h>
#include <hip/hip_bf16.h>

typedef __hip_bfloat16 bf16;

#define BBATCH 8
#define HHH 56
#define WWW 56
#define CCH 96          // C
#define DIN 192         // D
#define NST 16          // N
#define KDIR 4          // K
#define RDT 6           // R
#define LLEN 3136       // H*W
#define BLTOT 25088     // B*L
#define SSEG 32         // segments
#define SEGL 98         // L / SSEG
#define PJC 38          // R + 2N
#define PJW 152         // K * PJC
#define MLPH 384

__device__ __forceinline__ float b2f(bf16 v) { return __bfloat162float(v); }
__device__ __forceinline__ bf16  f2b(float v) { return __float2bfloat16(v); }
__device__ __forceinline__ float sigm(float x) { return 1.f / (1.f + __expf(-x)); }
__device__ __forceinline__ float softplusf(float x) {
    return fmaxf(x, 0.f) + log1pf(__expf(-fabsf(x)));
}
__device__ __forceinline__ float geluf(float v) {
    float u = 0.7978845608028654f * (v + 0.044715f * v * v * v);
    float ey = __expf(2.f * u);
    float th = 1.f - 2.f / (ey + 1.f);
    return 0.5f * v * (1.f + th);
}

// scan-step l -> spatial position (row-major h*56+w) for direction k
__device__ __forceinline__ int pos_map(int k, int l) {
    if (k & 2) l = LLEN - 1 - l;
    if (k & 1) { int q = l / WWW; int r = l - q * WWW; return r * WWW + q; }
    return l;
}

// ---- shared GEMM inner tile: 96-c chunk, 64-j tile, 64 positions -----------
__device__ __forceinline__ void gemm_tile_accum(const float* __restrict__ xt,
                                                const float* __restrict__ wt,
                                                int jj, int prow,
                                                float* __restrict__ a0,
                                                float* __restrict__ a1) {
#pragma unroll 2
    for (int c = 0; c < 96; ++c) {
        float w0 = wt[c * 65 + jj];
        float w1 = wt[c * 65 + jj + 32];
        const float4 xa = *(const float4*)&xt[c * 68 + prow];
        const float4 xb = *(const float4*)&xt[c * 68 + prow + 4];
        a0[0] = fmaf(w0, xa.x, a0[0]); a0[1] = fmaf(w0, xa.y, a0[1]);
        a0[2] = fmaf(w0, xa.z, a0[2]); a0[3] = fmaf(w0, xa.w, a0[3]);
        a0[4] = fmaf(w0, xb.x, a0[4]); a0[5] = fmaf(w0, xb.y, a0[5]);
        a0[6] = fmaf(w0, xb.z, a0[6]); a0[7] = fmaf(w0, xb.w, a0[7]);
        a1[0] = fmaf(w1, xa.x, a1[0]); a1[1] = fmaf(w1, xa.y, a1[1]);
        a1[2] = fmaf(w1, xa.z, a1[2]); a1[3] = fmaf(w1, xa.w, a1[3]);
        a1[4] = fmaf(w1, xb.x, a1[4]); a1[5] = fmaf(w1, xb.y, a1[5]);
        a1[6] = fmaf(w1, xb.z, a1[6]); a1[7] = fmaf(w1, xb.w, a1[7]);
    }
}

// ---- K1: LN1 + in_proj (96 -> 384), split to xc(bf16) / z(bf16) ------------
__global__ __launch_bounds__(256) void k1_ln_inproj(
    const float* __restrict__ x, const float* __restrict__ lnw,
    const float* __restrict__ lnb, const float* __restrict__ Wp,
    bf16* __restrict__ xcpre, bf16* __restrict__ z) {
    __shared__ float xt[96 * 68];
    __shared__ float wt[96 * 65];
    __shared__ float ps[256], pq[256];
    __shared__ float mrow[64], srow[64];
    const int t = threadIdx.x;
    const int P0 = blockIdx.x * 64;
    for (int q = t; q < 64 * 96; q += 256) {
        int pos = q / 96, c = q - pos * 96;
        xt[c * 68 + pos] = x[(size_t)P0 * 96 + q];
    }
    __syncthreads();
    {
        int pos = t & 63, part = t >> 6;
        float s = 0.f, s2 = 0.f;
        for (int i = 0; i < 24; ++i) {
            float v = xt[(part * 24 + i) * 68 + pos];
            s += v; s2 += v * v;
        }
        ps[part * 64 + pos] = s; pq[part * 64 + pos] = s2;
    }
    __syncthreads();
    if (t < 64) {
        float s = ps[t] + ps[64 + t] + ps[128 + t] + ps[192 + t];
        float s2 = pq[t] + pq[64 + t] + pq[128 + t] + pq[192 + t];
        float m = s * (1.f / 96.f);
        float v = s2 * (1.f / 96.f) - m * m;
        mrow[t] = m; srow[t] = rsqrtf(v + 1e-5f);
    }
    __syncthreads();
    for (int q = t; q < 64 * 96; q += 256) {
        int pos = q / 96, c = q - pos * 96;
        float v = xt[c * 68 + pos];
        xt[c * 68 + pos] = (v - mrow[pos]) * srow[pos] * lnw[c] + lnb[c];
    }
    const int lane = t & 63, wv = t >> 6, jj = lane & 31, ph = lane >> 5;
    const int prow = wv * 16 + ph * 8;
    for (int jt = 0; jt < 6; ++jt) {
        __syncthreads();
        for (int q = t; q < 64 * 96; q += 256) {
            int j = q / 96, c = q - j * 96;
            wt[c * 65 + j] = Wp[(size_t)(jt * 64 + j) * 96 + c];
        }
        __syncthreads();
        float a0[8] = {0,0,0,0,0,0,0,0}, a1[8] = {0,0,0,0,0,0,0,0};
        gemm_tile_accum(xt, wt, jj, prow, a0, a1);
        for (int m = 0; m < 2; ++m) {
            int j = jt * 64 + jj + 32 * m;
            const float* ac = m ? a1 : a0;
#pragma unroll
            for (int i = 0; i < 8; ++i) {
                int P = P0 + prow + i;
                if (j < DIN) xcpre[(size_t)P * DIN + j] = f2b(ac[i]);
                else         z[(size_t)P * DIN + (j - DIN)] = f2b(ac[i]);
            }
        }
    }
}

// ---- K2: depthwise 3x3 conv + bias + silu ----------------------------------
__global__ __launch_bounds__(256) void k2_conv(
    const bf16* __restrict__ xcpre, const float* __restrict__ cw,
    const float* __restrict__ cb, bf16* __restrict__ xconv) {
    int idx = blockIdx.x * 256 + threadIdx.x;
    int d = idx % DIN;
    int P = idx / DIN;
    int b = P / LLEN, l = P - b * LLEN;
    int h = l / WWW, w = l - h * WWW;
    float acc = cb[d];
#pragma unroll
    for (int i = 0; i < 3; ++i) {
        int hh = h + i - 1;
        if (hh < 0 || hh >= HHH) continue;
#pragma unroll
        for (int j = 0; j < 3; ++j) {
            int ww = w + j - 1;
            if (ww < 0 || ww >= WWW) continue;
            float xv = b2f(xcpre[((size_t)(b * LLEN + hh * WWW + ww)) * DIN + d]);
            acc = fmaf(xv, cw[d * 9 + i * 3 + j], acc);
        }
    }
    acc = acc * sigm(acc);
    xconv[(size_t)P * DIN + d] = f2b(acc);
}

// ---- K3: x_proj (192 -> 152 = K*(R+2N)), fp32 out --------------------------
__global__ __launch_bounds__(256) void k3_xproj(
    const bf16* __restrict__ xconv, const float* __restrict__ Wx,
    float* __restrict__ proj) {
    __shared__ float xt[96 * 68];
    __shared__ float wt[96 * 65];
    const int t = threadIdx.x;
    const int P0 = blockIdx.x * 64;
    const int lane = t & 63, wv = t >> 6, jj = lane & 31, ph = lane >> 5;
    const int prow = wv * 16 + ph * 8;
    for (int jt = 0; jt < 3; ++jt) {
        int j0 = jt * 64;
        int jcnt = (PJW - j0 < 64) ? (PJW - j0) : 64;
        float a0[8] = {0,0,0,0,0,0,0,0}, a1[8] = {0,0,0,0,0,0,0,0};
        for (int cc = 0; cc < 2; ++cc) {
            __syncthreads();
            for (int q = t; q < 64 * 96; q += 256) {
                int pos = q / 96, c = q - pos * 96;
                xt[c * 68 + pos] = b2f(xconv[(size_t)(P0 + pos) * DIN + cc * 96 + c]);
            }
            for (int q = t; q < jcnt * 96; q += 256) {
                int j = q / 96, c = q - j * 96;
                wt[c * 65 + j] = Wx[(size_t)(j0 + j) * DIN + cc * 96 + c];
            }
            __syncthreads();
            gemm_tile_accum(xt, wt, jj, prow, a0, a1);
        }
        for (int m = 0; m < 2; ++m) {
            int j = j0 + jj + 32 * m;
            if (j >= PJW) continue;
            const float* ac = m ? a1 : a0;
#pragma unroll
            for (int i = 0; i < 8; ++i)
                proj[(size_t)(P0 + prow + i) * PJW + j] = ac[i];
        }
        __syncthreads();
    }
}

// ---- K4: scan pass 1 — per-segment local h_end and sum(dt) -----------------
__global__ __launch_bounds__(192) void k4_scan1(
    const bf16* __restrict__ xconv, const float* __restrict__ proj,
    const float* __restrict__ dtw, const float* __restrict__ dtb,
    const float* __restrict__ Alog, float* __restrict__ hloc,
    float* __restrict__ tsum) {
    __shared__ float pl[49 * PJC];
    const int bid = blockIdx.x;
    const int s = bid & 31, k = (bid >> 5) & 3, b = bid >> 7;
    const int d = threadIdx.x;
    float w6[RDT];
#pragma unroll
    for (int r = 0; r < RDT; ++r) w6[r] = dtw[(k * DIN + d) * RDT + r];
    const float bias = dtb[k * DIN + d];
    float a[NST];
#pragma unroll
    for (int n = 0; n < NST; ++n) a[n] = -__expf(Alog[(k * DIN + d) * NST + n]);
    float h[NST];
#pragma unroll
    for (int n = 0; n < NST; ++n) h[n] = 0.f;
    float T = 0.f;
    const int l0 = s * SEGL;
    for (int half = 0; half < 2; ++half) {
        __syncthreads();
        for (int q = d; q < 49 * PJC; q += 192) {
            int st = q / PJC, c = q - st * PJC;
            int p = pos_map(k, l0 + half * 49 + st);
            pl[q] = proj[(size_t)(b * LLEN + p) * PJW + k * PJC + c];
        }
        __syncthreads();
        for (int st = 0; st < 49; ++st) {
            int p = pos_map(k, l0 + half * 49 + st);
            float xv = b2f(xconv[(size_t)(b * LLEN + p) * DIN + d]);
            const float* row = &pl[st * PJC];
            float dtv = bias;
#pragma unroll
            for (int r = 0; r < RDT; ++r) dtv = fmaf(row[r], w6[r], dtv);
            dtv = softplusf(dtv);
            T += dtv;
            float u = dtv * xv;
#pragma unroll
            for (int n = 0; n < NST; ++n) {
                float e = __expf(dtv * a[n]);
                h[n] = fmaf(h[n], e, u * row[RDT + n]);
            }
        }
    }
    size_t base = ((size_t)bid * DIN + d) * NST;
#pragma unroll
    for (int n = 0; n < NST; ++n) hloc[base + n] = h[n];
    tsum[bid * DIN + d] = T;
}

// ---- K5: exact segment carries ---------------------------------------------
__global__ __launch_bounds__(256) void k5_carry(
    const float* __restrict__ hloc, const float* __restrict__ tsum,
    const float* __restrict__ Alog, float* __restrict__ hin) {
    int g = blockIdx.x * 256 + threadIdx.x;   // over B*K*D*N
    int n = g & 15;
    int dk = g >> 4;
    int d = dk % DIN;
    int bk = dk / DIN;                        // b*4 + k
    int k = bk & 3;
    float a = -__expf(Alog[(k * DIN + d) * NST + n]);
    float Hc = 0.f;
    for (int s = 0; s < SSEG; ++s) {
        int bid = bk * SSEG + s;
        size_t idx = ((size_t)bid * DIN + d) * NST + n;
        hin[idx] = Hc;
        float hl = hloc[idx];
        float Tv = tsum[bid * DIN + d];
        Hc = fmaf(__expf(a * Tv), Hc, hl);
    }
}

// ---- K6: scan pass 2 — exact scan from carries, emit y (merged pos) --------
__global__ __launch_bounds__(192) void k6_scan2(
    const bf16* __restrict__ xconv, const float* __restrict__ proj,
    const float* __restrict__ dtw, const float* __restrict__ dtb,
    const float* __restrict__ Alog, const float* __restrict__ Dsp,
    const float* __restrict__ hin, bf16* __restrict__ ysm) {
    __shared__ float pl[49 * PJC];
    const int bid = blockIdx.x;
    const int s = bid & 31, k = (bid >> 5) & 3, b = bid >> 7;
    const int d = threadIdx.x;
    float w6[RDT];
#pragma unroll
    for (int r = 0; r < RDT; ++r) w6[r] = dtw[(k * DIN + d) * RDT + r];
    const float bias = dtb[k * DIN + d];
    const float dsv = Dsp[k * DIN + d];
    float a[NST];
#pragma unroll
    for (int n = 0; n < NST; ++n) a[n] = -__expf(Alog[(k * DIN + d) * NST + n]);
    float h[NST];
    size_t hbase = ((size_t)bid * DIN + d) * NST;
#pragma unroll
    for (int n = 0; n < NST; ++n) h[n] = hin[hbase + n];
    const int l0 = s * SEGL;
    for (int half = 0; half < 2; ++half) {
        __syncthreads();
        for (int q = d; q < 49 * PJC; q += 192) {
            int st = q / PJC, c = q - st * PJC;
            int p = pos_map(k, l0 + half * 49 + st);
            pl[q] = proj[(size_t)(b * LLEN + p) * PJW + k * PJC + c];
        }
        __syncthreads();
        for (int st = 0; st < 49; ++st) {
            int p = pos_map(k, l0 + half * 49 + st);
            float xv = b2f(xconv[(size_t)(b * LLEN + p) * DIN + d]);
            const float* row = &pl[st * PJC];
            float dtv = bias;
#pragma unroll
            for (int r = 0; r < RDT; ++r) dtv = fmaf(row[r], w6[r], dtv);
            dtv = softplusf(dtv);
            float u = dtv * xv;
            float y = dsv * xv;
#pragma unroll
            for (int n = 0; n < NST; ++n) {
                float e = __expf(dtv * a[n]);
                h[n] = fmaf(h[n], e, u * row[RDT + n]);
                y = fmaf(h[n], row[RDT + NST + n], y);
            }
            ysm[(size_t)((b * KDIR + k) * LLEN + p) * DIN + d] = f2b(y);
        }
    }
}

// ---- K6.5: merge 4 planes + out_norm LN + *silu(z) -------------------------
__global__ __launch_bounds__(256) void k65_merge(
    const bf16* __restrict__ ysm, const bf16* __restrict__ z,
    const float* __restrict__ onw, const float* __restrict__ onb,
    bf16* __restrict__ ymod) {
    __shared__ float rb[16 * DIN];
    __shared__ float ps[256], pq[256];
    __shared__ float mrow[16], srow[16];
    const int t = threadIdx.x;
    const int P0 = blockIdx.x * 16;
    for (int q = t; q < 16 * DIN; q += 256) {
        int pos = q / DIN, c = q - pos * DIN;
        int P = P0 + pos;
        int b = P / LLEN, l = P - b * LLEN;
        size_t base = ((size_t)(b * KDIR) * LLEN + l) * DIN + c;
        size_t pstr = (size_t)LLEN * DIN;
        float v = b2f(ysm[base]) + b2f(ysm[base + pstr]) +
                  b2f(ysm[base + 2 * pstr]) + b2f(ysm[base + 3 * pstr]);
        rb[q] = v;
    }
    __syncthreads();
    {
        int pos = t >> 4, part = t & 15;
        float s = 0.f, s2 = 0.f;
        for (int i = 0; i < 12; ++i) {
            float v = rb[pos * DIN + part * 12 + i];
            s += v; s2 += v * v;
        }
        ps[pos * 16 + part] = s; pq[pos * 16 + part] = s2;
    }
    __syncthreads();
    if (t < 16) {
        float s = 0.f, s2 = 0.f;
        for (int i = 0; i < 16; ++i) { s += ps[t * 16 + i]; s2 += pq[t * 16 + i]; }
        float m = s * (1.f / DIN);
        float v = s2 * (1.f / DIN) - m * m;
        mrow[t] = m; srow[t] = rsqrtf(v + 1e-5f);
    }
    __syncthreads();
    for (int q = t; q < 16 * DIN; q += 256) {
        int pos = q / DIN, c = q - pos * DIN;
        int P = P0 + pos;
        float v = (rb[q] - mrow[pos]) * srow[pos] * onw[c] + onb[c];
        float zv = b2f(z[(size_t)P * DIN + c]);
        v *= zv * sigm(zv);
        ymod[(size_t)P * DIN + c] = f2b(v);
    }
}

// ---- K7: out_proj (192 -> 96) + residual x ---------------------------------
__global__ __launch_bounds__(256) void k7_outproj(
    const bf16* __restrict__ ymod, const float* __restrict__ Wo,
    const float* __restrict__ xin, float* __restrict__ y1) {
    __shared__ float xt[96 * 68];
    __shared__ float wt[96 * 65];
    const int t = threadIdx.x;
    const int P0 = blockIdx.x * 64;
    const int lane = t & 63, wv = t >> 6, jj = lane & 31, ph = lane >> 5;
    const int prow = wv * 16 + ph * 8;
    for (int jt = 0; jt < 2; ++jt) {
        int j0 = jt * 64;
        int jcnt = (96 - j0 < 64) ? (96 - j0) : 64;
        float a0[8] = {0,0,0,0,0,0,0,0}, a1[8] = {0,0,0,0,0,0,0,0};
        for (int cc = 0; cc < 2; ++cc) {
            __syncthreads();
            for (int q = t; q < 64 * 96; q += 256) {
                int pos = q / 96, c = q - pos * 96;
                xt[c * 68 + pos] = b2f(ymod[(size_t)(P0 + pos) * DIN + cc * 96 + c]);
            }
            for (int q = t; q < jcnt * 96; q += 256) {
                int j = q / 96, c = q - j * 96;
                wt[c * 65 + j] = Wo[(size_t)(j0 + j) * DIN + cc * 96 + c];
            }
            __syncthreads();
            gemm_tile_accum(xt, wt, jj, prow, a0, a1);
        }
        for (int m = 0; m < 2; ++m) {
            int j = j0 + jj + 32 * m;
            if (j >= 96) continue;
            const float* ac = m ? a1 : a0;
#pragma unroll
            for (int i = 0; i < 8; ++i) {
                size_t P = (size_t)(P0 + prow + i);
                y1[P * CCH + j] = xin[P * CCH + j] + ac[i];
            }
        }
        __syncthreads();
    }
}

// ---- K8: LN2 + fc1 (96 -> 384) + gelu --------------------------------------
__global__ __launch_bounds__(256) void k8_mlp1(
    const float* __restrict__ y1, const float* __restrict__ lnw,
    const float* __restrict__ lnb, const float* __restrict__ W1,
    const float* __restrict__ b1, bf16* __restrict__ hmlp) {
    __shared__ float xt[96 * 68];
    __shared__ float wt[96 * 65];
    __shared__ float ps[256], pq[256];
    __shared__ float mrow[64], srow[64];
    const int t = threadIdx.x;
    const int P0 = blockIdx.x * 64;
    for (int q = t; q < 64 * 96; q += 256) {
        int pos = q / 96, c = q - pos * 96;
        xt[c * 68 + pos] = y1[(size_t)P0 * 96 + q];
    }
    __syncthreads();
    {
        int pos = t & 63, part = t >> 6;
        float s = 0.f, s2 = 0.f;
        for (int i = 0; i < 24; ++i) {
            float v = xt[(part * 24 + i) * 68 + pos];
            s += v; s2 += v * v;
        }
        ps[part * 64 + pos] = s; pq[part * 64 + pos] = s2;
    }
    __syncthreads();
    if (t < 64) {
        float s = ps[t] + ps[64 + t] + ps[128 + t] + ps[192 + t];
        float s2 = pq[t] + pq[64 + t] + pq[128 + t] + pq[192 + t];
        float m = s * (1.f / 96.f);
        float v = s2 * (1.f / 96.f) - m * m;
        mrow[t] = m; srow[t] = rsqrtf(v + 1e-5f);
    }
    __syncthreads();
    for (int q = t; q < 64 * 96; q += 256) {
        int pos = q / 96, c = q - pos * 96;
        float v = xt[c * 68 + pos];
        xt[c * 68 + pos] = (v - mrow[pos]) * srow[pos] * lnw[c] + lnb[c];
    }
    const int lane = t & 63, wv = t >> 6, jj = lane & 31, ph = lane >> 5;
    const int prow = wv * 16 + ph * 8;
    for (int jt = 0; jt < 6; ++jt) {
        __syncthreads();
        for (int q = t; q < 64 * 96; q += 256) {
            int j = q / 96, c = q - j * 96;
            wt[c * 65 + j] = W1[(size_t)(jt * 64 + j) * 96 + c];
        }
        __syncthreads();
        float a0[8] = {0,0,0,0,0,0,0,0}, a1[8] = {0,0,0,0,0,0,0,0};
        gemm_tile_accum(xt, wt, jj, prow, a0, a1);
        for (int m = 0; m < 2; ++m) {
            int j = jt * 64 + jj + 32 * m;
            const float* ac = m ? a1 : a0;
            float bj = b1[j];
#pragma unroll
            for (int i = 0; i < 8; ++i) {
                int P = P0 + prow + i;
                hmlp[(size_t)P * MLPH + j] = f2b(geluf(ac[i] + bj));
            }
        }
    }
}

// ---- K9: fc2 (384 -> 96) + bias + residual -> out --------------------------
__global__ __launch_bounds__(256) void k9_mlp2(
    const bf16* __restrict__ hmlp, const float* __restrict__ W2,
    const float* __restrict__ b2, const float* __restrict__ y1,
    float* __restrict__ out) {
    __shared__ float xt[96 * 68];
    __shared__ float wt[96 * 65];
    const int t = threadIdx.x;
    const int P0 = blockIdx.x * 64;
    const int lane = t & 63, wv = t >> 6, jj = lane & 31, ph = lane >> 5;
    const int prow = wv * 16 + ph * 8;
    for (int jt = 0; jt < 2; ++jt) {
        int j0 = jt * 64;
        int jcnt = (96 - j0 < 64) ? (96 - j0) : 64;
        float a0[8] = {0,0,0,0,0,0,0,0}, a1[8] = {0,0,0,0,0,0,0,0};
        for (int cc = 0; cc < 4; ++cc) {
            __syncthreads();
            for (int q = t; q < 64 * 96; q += 256) {
                int pos = q / 96, c = q - pos * 96;
                xt[c * 68 + pos] = b2f(hmlp[(size_t)(P0 + pos) * MLPH + cc * 96 + c]);
            }
            for (int q = t; q < jcnt * 96; q += 256) {
                int j = q / 96, c = q - j * 96;
                wt[c * 65 + j] = W2[(size_t)(j0 + j) * MLPH + cc * 96 + c];
            }
            __syncthreads();
            gemm_tile_accum(xt, wt, jj, prow, a0, a1);
        }
        for (int m = 0; m < 2; ++m) {
            int j = j0 + jj + 32 * m;
            if (j >= 96) continue;
            const float* ac = m ? a1 : a0;
            float bj = b2[j];
#pragma unroll
            for (int i = 0; i < 8; ++i) {
                size_t P = (size_t)(P0 + prow + i);
                out[P * CCH + j] = y1[P * CCH + j] + bj + ac[i];
            }
        }
        __syncthreads();
    }
}

extern "C" void kernel_launch(void* const* d_in, const int* in_sizes, int n_in,
                              void* d_out, int out_size, void* d_ws, size_t ws_size,
                              hipStream_t stream) {
    const float* x      = (const float*)d_in[0];
    const float* ln1w   = (const float*)d_in[1];
    const float* ln1b   = (const float*)d_in[2];
    const float* inpW   = (const float*)d_in[3];
    const float* convW  = (const float*)d_in[4];
    const float* convB  = (const float*)d_in[5];
    const float* xprojW = (const float*)d_in[6];
    const float* dtW    = (const float*)d_in[7];
    const float* dtB    = (const float*)d_in[8];
    const float* Alog   = (const float*)d_in[9];
    const float* Dsp    = (const float*)d_in[10];
    const float* onw    = (const float*)d_in[11];
    const float* onb    = (const float*)d_in[12];
    const float* outW   = (const float*)d_in[13];
    const float* ln2w   = (const float*)d_in[14];
    const float* ln2b   = (const float*)d_in[15];
    const float* fc1W   = (const float*)d_in[16];
    const float* fc1b   = (const float*)d_in[17];
    const float* fc2W   = (const float*)d_in[18];
    const float* fc2b   = (const float*)d_in[19];
    float* out = (float*)d_out;

    char* ws = (char*)d_ws;
    bf16*  z_bf     = (bf16*)(ws + 0);            //  9,633,792
    bf16*  xcpre_bf = (bf16*)(ws + 9633792);      //  9,633,792
    bf16*  xconv_bf = (bf16*)(ws + 19267584);     //  9,633,792
    float* proj_f   = (float*)(ws + 28901376);    // 15,253,504
    float* hloc_f   = (float*)(ws + 44154880);    // 12,582,912
    float* tsum_f   = (float*)(ws + 56737792);    //    786,432
    float* hin_f    = (float*)(ws + 57524224);    // 12,582,912
    bf16*  ysm_bf   = (bf16*)(ws + 70107136);     // 38,535,168
    bf16*  ymod_bf  = (bf16*)(ws + 108642304);    //  9,633,792
    float* y1_f     = (float*)(ws + 118276096);   //  9,633,792  (end ~127.9 MB)
    bf16*  hmlp_bf  = (bf16*)(ws + 70107136);     // aliases ysm (free after k65)

    k1_ln_inproj<<<392, 256, 0, stream>>>(x, ln1w, ln1b, inpW, xcpre_bf, z_bf);
    k2_conv<<<18816, 256, 0, stream>>>(xcpre_bf, convW, convB, xconv_bf);
    k3_xproj<<<392, 256, 0, stream>>>(xconv_bf, xprojW, proj_f);
    k4_scan1<<<1024, 192, 0, stream>>>(xconv_bf, proj_f, dtW, dtB, Alog, hloc_f, tsum_f);
    k5_carry<<<384, 256, 0, stream>>>(hloc_f, tsum_f, Alog, hin_f);
    k6_scan2<<<1024, 192, 0, stream>>>(xconv_bf, proj_f, dtW, dtB, Alog, Dsp, hin_f, ysm_bf);
    k65_merge<<<1568, 256, 0, stream>>>(ysm_bf, z_bf, onw, onb, ymod_bf);
    k7_outproj<<<392, 256, 0, stream>>>(ymod_bf, outW, x, y1_f);
    k8_mlp1<<<392, 256, 0, stream>>>(y1_f, ln2w, ln2b, fc1W, fc1b, hmlp_bf);
    k9_mlp2<<<392, 256, 0, stream>>>(hmlp_bf, fc2W, fc2b, y1_f, out);
}

// Round 2
// 613.936 us; speedup vs baseline: 1.2686x; 1.2686x over previous
//
#include <hip/hip_runtime.h>
#include <hip/hip_bf16.h>

typedef __hip_bfloat16 bf16;

#define BBATCH 8
#define HHH 56
#define WWW 56
#define CCH 96          // C
#define DIN 192         // D
#define NST 16          // N
#define KDIR 4          // K
#define RDT 6           // R
#define LLEN 3136       // H*W
#define BLTOT 25088     // B*L
#define SSEG 64         // segments
#define SEGL 49         // L / SSEG
#define PJC 38          // R + 2N
#define PJW 152         // K * PJC
#define PJS 40          // padded LDS row stride (16B aligned)
#define PJS1 24         // pass-1 padded row stride (r+B only)
#define MLPH 384

__device__ __forceinline__ float b2f(bf16 v) { return __bfloat162float(v); }
__device__ __forceinline__ bf16  f2b(float v) { return __float2bfloat16(v); }
__device__ __forceinline__ float sigm(float x) { return 1.f / (1.f + __expf(-x)); }
__device__ __forceinline__ float softplusf(float x) {
    return fmaxf(x, 0.f) + __logf(1.f + __expf(-fabsf(x)));
}
__device__ __forceinline__ float geluf(float v) {
    float u = 0.7978845608028654f * (v + 0.044715f * v * v * v);
    float ey = __expf(2.f * u);
    float th = 1.f - 2.f / (ey + 1.f);
    return 0.5f * v * (1.f + th);
}

// scan-step l -> spatial position (row-major h*56+w) for direction k
__device__ __forceinline__ int pos_map(int k, int l) {
    if (k & 2) l = LLEN - 1 - l;
    if (k & 1) { int q = l / WWW; int r = l - q * WWW; return r * WWW + q; }
    return l;
}

// ---- shared GEMM inner tile: 96-c chunk, 64-j tile, 64 positions -----------
__device__ __forceinline__ void gemm_tile_accum(const float* __restrict__ xt,
                                                const float* __restrict__ wt,
                                                int jj, int prow,
                                                float* __restrict__ a0,
                                                float* __restrict__ a1) {
#pragma unroll 2
    for (int c = 0; c < 96; ++c) {
        float w0 = wt[c * 65 + jj];
        float w1 = wt[c * 65 + jj + 32];
        const float4 xa = *(const float4*)&xt[c * 68 + prow];
        const float4 xb = *(const float4*)&xt[c * 68 + prow + 4];
        a0[0] = fmaf(w0, xa.x, a0[0]); a0[1] = fmaf(w0, xa.y, a0[1]);
        a0[2] = fmaf(w0, xa.z, a0[2]); a0[3] = fmaf(w0, xa.w, a0[3]);
        a0[4] = fmaf(w0, xb.x, a0[4]); a0[5] = fmaf(w0, xb.y, a0[5]);
        a0[6] = fmaf(w0, xb.z, a0[6]); a0[7] = fmaf(w0, xb.w, a0[7]);
        a1[0] = fmaf(w1, xa.x, a1[0]); a1[1] = fmaf(w1, xa.y, a1[1]);
        a1[2] = fmaf(w1, xa.z, a1[2]); a1[3] = fmaf(w1, xa.w, a1[3]);
        a1[4] = fmaf(w1, xb.x, a1[4]); a1[5] = fmaf(w1, xb.y, a1[5]);
        a1[6] = fmaf(w1, xb.z, a1[6]); a1[7] = fmaf(w1, xb.w, a1[7]);
    }
}

// ---- K1: LN1 + in_proj (96 -> 384), split to xc(bf16) / z(bf16) ------------
__global__ __launch_bounds__(256) void k1_ln_inproj(
    const float* __restrict__ x, const float* __restrict__ lnw,
    const float* __restrict__ lnb, const float* __restrict__ Wp,
    bf16* __restrict__ xcpre, bf16* __restrict__ z) {
    __shared__ float xt[96 * 68];
    __shared__ float wt[96 * 65];
    __shared__ float ps[256], pq[256];
    __shared__ float mrow[64], srow[64];
    const int t = threadIdx.x;
    const int P0 = blockIdx.x * 64;
    for (int q = t; q < 64 * 96; q += 256) {
        int pos = q / 96, c = q - pos * 96;
        xt[c * 68 + pos] = x[(size_t)P0 * 96 + q];
    }
    __syncthreads();
    {
        int pos = t & 63, part = t >> 6;
        float s = 0.f, s2 = 0.f;
        for (int i = 0; i < 24; ++i) {
            float v = xt[(part * 24 + i) * 68 + pos];
            s += v; s2 += v * v;
        }
        ps[part * 64 + pos] = s; pq[part * 64 + pos] = s2;
    }
    __syncthreads();
    if (t < 64) {
        float s = ps[t] + ps[64 + t] + ps[128 + t] + ps[192 + t];
        float s2 = pq[t] + pq[64 + t] + pq[128 + t] + pq[192 + t];
        float m = s * (1.f / 96.f);
        float v = s2 * (1.f / 96.f) - m * m;
        mrow[t] = m; srow[t] = rsqrtf(v + 1e-5f);
    }
    __syncthreads();
    for (int q = t; q < 64 * 96; q += 256) {
        int pos = q / 96, c = q - pos * 96;
        float v = xt[c * 68 + pos];
        xt[c * 68 + pos] = (v - mrow[pos]) * srow[pos] * lnw[c] + lnb[c];
    }
    const int lane = t & 63, wv = t >> 6, jj = lane & 31, ph = lane >> 5;
    const int prow = wv * 16 + ph * 8;
    for (int jt = 0; jt < 6; ++jt) {
        __syncthreads();
        for (int q = t; q < 64 * 96; q += 256) {
            int j = q / 96, c = q - j * 96;
            wt[c * 65 + j] = Wp[(size_t)(jt * 64 + j) * 96 + c];
        }
        __syncthreads();
        float a0[8] = {0,0,0,0,0,0,0,0}, a1[8] = {0,0,0,0,0,0,0,0};
        gemm_tile_accum(xt, wt, jj, prow, a0, a1);
        for (int m = 0; m < 2; ++m) {
            int j = jt * 64 + jj + 32 * m;
            const float* ac = m ? a1 : a0;
#pragma unroll
            for (int i = 0; i < 8; ++i) {
                int P = P0 + prow + i;
                if (j < DIN) xcpre[(size_t)P * DIN + j] = f2b(ac[i]);
                else         z[(size_t)P * DIN + (j - DIN)] = f2b(ac[i]);
            }
        }
    }
}

// ---- K2: depthwise 3x3 conv + bias + silu ----------------------------------
__global__ __launch_bounds__(256) void k2_conv(
    const bf16* __restrict__ xcpre, const float* __restrict__ cw,
    const float* __restrict__ cb, bf16* __restrict__ xconv) {
    int idx = blockIdx.x * 256 + threadIdx.x;
    int d = idx % DIN;
    int P = idx / DIN;
    int b = P / LLEN, l = P - b * LLEN;
    int h = l / WWW, w = l - h * WWW;
    float acc = cb[d];
#pragma unroll
    for (int i = 0; i < 3; ++i) {
        int hh = h + i - 1;
        if (hh < 0 || hh >= HHH) continue;
#pragma unroll
        for (int j = 0; j < 3; ++j) {
            int ww = w + j - 1;
            if (ww < 0 || ww >= WWW) continue;
            float xv = b2f(xcpre[((size_t)(b * LLEN + hh * WWW + ww)) * DIN + d]);
            acc = fmaf(xv, cw[d * 9 + i * 3 + j], acc);
        }
    }
    acc = acc * sigm(acc);
    xconv[(size_t)P * DIN + d] = f2b(acc);
}

// ---- K3: x_proj (192 -> 152 = K*(R+2N)), fp32 out --------------------------
__global__ __launch_bounds__(256) void k3_xproj(
    const bf16* __restrict__ xconv, const float* __restrict__ Wx,
    float* __restrict__ proj) {
    __shared__ float xt[96 * 68];
    __shared__ float wt[96 * 65];
    const int t = threadIdx.x;
    const int P0 = blockIdx.x * 64;
    const int lane = t & 63, wv = t >> 6, jj = lane & 31, ph = lane >> 5;
    const int prow = wv * 16 + ph * 8;
    for (int jt = 0; jt < 3; ++jt) {
        int j0 = jt * 64;
        int jcnt = (PJW - j0 < 64) ? (PJW - j0) : 64;
        float a0[8] = {0,0,0,0,0,0,0,0}, a1[8] = {0,0,0,0,0,0,0,0};
        for (int cc = 0; cc < 2; ++cc) {
            __syncthreads();
            for (int q = t; q < 64 * 96; q += 256) {
                int pos = q / 96, c = q - pos * 96;
                xt[c * 68 + pos] = b2f(xconv[(size_t)(P0 + pos) * DIN + cc * 96 + c]);
            }
            for (int q = t; q < jcnt * 96; q += 256) {
                int j = q / 96, c = q - j * 96;
                wt[c * 65 + j] = Wx[(size_t)(j0 + j) * DIN + cc * 96 + c];
            }
            __syncthreads();
            gemm_tile_accum(xt, wt, jj, prow, a0, a1);
        }
        for (int m = 0; m < 2; ++m) {
            int j = j0 + jj + 32 * m;
            if (j >= PJW) continue;
            const float* ac = m ? a1 : a0;
#pragma unroll
            for (int i = 0; i < 8; ++i)
                proj[(size_t)(P0 + prow + i) * PJW + j] = ac[i];
        }
        __syncthreads();
    }
}

// ---- K4: scan pass 1 — per-segment local h_end and sum(dt) -----------------
__global__ __launch_bounds__(192) void k4_scan1(
    const bf16* __restrict__ xconv, const float* __restrict__ proj,
    const float* __restrict__ dtw, const float* __restrict__ dtb,
    const float* __restrict__ Alog, float* __restrict__ hloc,
    float* __restrict__ tsum) {
    __shared__ float pl[SEGL * PJS1];
    __shared__ int posl[SEGL];
    const int bid = blockIdx.x;
    const int s = bid & 63, k = (bid >> 6) & 3, b = bid >> 8;
    const int d = threadIdx.x;
    const int l0 = s * SEGL;
    // stage: r + B columns (22), realigned: r at 0-5, B at 8-23
    for (int q = d; q < SEGL * 22; q += 192) {
        int st = q / 22, c = q - st * 22;
        int p = pos_map(k, l0 + st);
        int ofs = (c < 6) ? c : c + 2;
        pl[st * PJS1 + ofs] = proj[(size_t)(b * LLEN + p) * PJW + k * PJC + c];
    }
    if (d < SEGL) posl[d] = pos_map(k, l0 + d) * DIN;
    float w6[RDT];
#pragma unroll
    for (int r = 0; r < RDT; ++r) w6[r] = dtw[(k * DIN + d) * RDT + r];
    const float bias = dtb[k * DIN + d];
    float a[NST];
#pragma unroll
    for (int n = 0; n < NST; ++n) a[n] = -__expf(Alog[(k * DIN + d) * NST + n]);
    float h[NST];
#pragma unroll
    for (int n = 0; n < NST; ++n) h[n] = 0.f;
    float T = 0.f;
    __syncthreads();
    const bf16* xg = xconv + (size_t)b * LLEN * DIN + d;
    for (int bt = 0; bt < 7; ++bt) {
        int off7[7]; float xv7[7];
#pragma unroll
        for (int i = 0; i < 7; ++i) off7[i] = posl[bt * 7 + i];
#pragma unroll
        for (int i = 0; i < 7; ++i) xv7[i] = b2f(xg[off7[i]]);
#pragma unroll
        for (int i = 0; i < 7; ++i) {
            const float* rowf = &pl[(bt * 7 + i) * PJS1];
            float4 g0 = *(const float4*)(rowf);
            float2 g1 = *(const float2*)(rowf + 4);
            float dtv = bias;
            dtv = fmaf(g0.x, w6[0], dtv); dtv = fmaf(g0.y, w6[1], dtv);
            dtv = fmaf(g0.z, w6[2], dtv); dtv = fmaf(g0.w, w6[3], dtv);
            dtv = fmaf(g1.x, w6[4], dtv); dtv = fmaf(g1.y, w6[5], dtv);
            dtv = softplusf(dtv);
            T += dtv;
            float u = dtv * xv7[i];
#pragma unroll
            for (int g = 0; g < 4; ++g) {
                float4 Bv = *(const float4*)(rowf + 8 + 4 * g);
                float e0 = __expf(dtv * a[4 * g + 0]);
                float e1 = __expf(dtv * a[4 * g + 1]);
                float e2 = __expf(dtv * a[4 * g + 2]);
                float e3 = __expf(dtv * a[4 * g + 3]);
                h[4 * g + 0] = fmaf(h[4 * g + 0], e0, u * Bv.x);
                h[4 * g + 1] = fmaf(h[4 * g + 1], e1, u * Bv.y);
                h[4 * g + 2] = fmaf(h[4 * g + 2], e2, u * Bv.z);
                h[4 * g + 3] = fmaf(h[4 * g + 3], e3, u * Bv.w);
            }
        }
    }
    size_t base = ((size_t)bid * DIN + d) * NST;
#pragma unroll
    for (int n = 0; n < NST; ++n) hloc[base + n] = h[n];
    tsum[bid * DIN + d] = T;
}

// ---- K5: exact segment carries (hin may alias hloc: read-before-write) -----
__global__ __launch_bounds__(256) void k5_carry(
    const float* hloc, const float* __restrict__ tsum,
    const float* __restrict__ Alog, float* hin) {
    int g = blockIdx.x * 256 + threadIdx.x;   // over B*K*D*N
    int n = g & 15;
    int dk = g >> 4;
    int d = dk % DIN;
    int bk = dk / DIN;                        // b*4 + k
    int k = bk & 3;
    float a = -__expf(Alog[(k * DIN + d) * NST + n]);
    float Hc = 0.f;
    for (int s = 0; s < SSEG; ++s) {
        int bid = bk * SSEG + s;
        size_t idx = ((size_t)bid * DIN + d) * NST + n;
        float hl = hloc[idx];
        float Tv = tsum[bid * DIN + d];
        hin[idx] = Hc;
        Hc = fmaf(__expf(a * Tv), Hc, hl);
    }
}

// ---- K6: scan pass 2 — exact scan from carries, emit y (merged pos) --------
__global__ __launch_bounds__(192) void k6_scan2(
    const bf16* __restrict__ xconv, const float* __restrict__ proj,
    const float* __restrict__ dtw, const float* __restrict__ dtb,
    const float* __restrict__ Alog, const float* __restrict__ Dsp,
    const float* __restrict__ hin, bf16* __restrict__ ysm) {
    __shared__ float pl[SEGL * PJS];
    __shared__ int posl[SEGL];
    const int bid = blockIdx.x;
    const int s = bid & 63, k = (bid >> 6) & 3, b = bid >> 8;
    const int d = threadIdx.x;
    const int l0 = s * SEGL;
    // stage: r at 0-5, B at 8-23, C at 24-39
    for (int q = d; q < SEGL * PJC; q += 192) {
        int st = q / PJC, c = q - st * PJC;
        int p = pos_map(k, l0 + st);
        int ofs = (c < 6) ? c : c + 2;
        pl[st * PJS + ofs] = proj[(size_t)(b * LLEN + p) * PJW + k * PJC + c];
    }
    if (d < SEGL) posl[d] = pos_map(k, l0 + d) * DIN;
    float w6[RDT];
#pragma unroll
    for (int r = 0; r < RDT; ++r) w6[r] = dtw[(k * DIN + d) * RDT + r];
    const float bias = dtb[k * DIN + d];
    const float dsv = Dsp[k * DIN + d];
    float a[NST];
#pragma unroll
    for (int n = 0; n < NST; ++n) a[n] = -__expf(Alog[(k * DIN + d) * NST + n]);
    float h[NST];
    size_t hbase = ((size_t)bid * DIN + d) * NST;
#pragma unroll
    for (int n = 0; n < NST; ++n) h[n] = hin[hbase + n];
    __syncthreads();
    const bf16* xg = xconv + (size_t)b * LLEN * DIN + d;
    bf16* ysg = ysm + ((size_t)(b * KDIR + k) * LLEN) * DIN + d;
    for (int bt = 0; bt < 7; ++bt) {
        int off7[7]; float xv7[7];
#pragma unroll
        for (int i = 0; i < 7; ++i) off7[i] = posl[bt * 7 + i];
#pragma unroll
        for (int i = 0; i < 7; ++i) xv7[i] = b2f(xg[off7[i]]);
#pragma unroll
        for (int i = 0; i < 7; ++i) {
            const float* rowf = &pl[(bt * 7 + i) * PJS];
            float4 g0 = *(const float4*)(rowf);
            float2 g1 = *(const float2*)(rowf + 4);
            float dtv = bias;
            dtv = fmaf(g0.x, w6[0], dtv); dtv = fmaf(g0.y, w6[1], dtv);
            dtv = fmaf(g0.z, w6[2], dtv); dtv = fmaf(g0.w, w6[3], dtv);
            dtv = fmaf(g1.x, w6[4], dtv); dtv = fmaf(g1.y, w6[5], dtv);
            dtv = softplusf(dtv);
            float u = dtv * xv7[i];
            float y = dsv * xv7[i];
#pragma unroll
            for (int g = 0; g < 4; ++g) {
                float4 Bv = *(const float4*)(rowf + 8 + 4 * g);
                float4 Cv = *(const float4*)(rowf + 24 + 4 * g);
                float e0 = __expf(dtv * a[4 * g + 0]);
                float e1 = __expf(dtv * a[4 * g + 1]);
                float e2 = __expf(dtv * a[4 * g + 2]);
                float e3 = __expf(dtv * a[4 * g + 3]);
                h[4 * g + 0] = fmaf(h[4 * g + 0], e0, u * Bv.x);
                h[4 * g + 1] = fmaf(h[4 * g + 1], e1, u * Bv.y);
                h[4 * g + 2] = fmaf(h[4 * g + 2], e2, u * Bv.z);
                h[4 * g + 3] = fmaf(h[4 * g + 3], e3, u * Bv.w);
                y = fmaf(h[4 * g + 0], Cv.x, y);
                y = fmaf(h[4 * g + 1], Cv.y, y);
                y = fmaf(h[4 * g + 2], Cv.z, y);
                y = fmaf(h[4 * g + 3], Cv.w, y);
            }
            ysg[off7[i]] = f2b(y);
        }
    }
}

// ---- K6.5: merge 4 planes + out_norm LN + *silu(z) -------------------------
__global__ __launch_bounds__(256) void k65_merge(
    const bf16* __restrict__ ysm, const bf16* __restrict__ z,
    const float* __restrict__ onw, const float* __restrict__ onb,
    bf16* __restrict__ ymod) {
    __shared__ float rb[16 * DIN];
    __shared__ float ps[256], pq[256];
    __shared__ float mrow[16], srow[16];
    const int t = threadIdx.x;
    const int P0 = blockIdx.x * 16;
    for (int q = t; q < 16 * DIN; q += 256) {
        int pos = q / DIN, c = q - pos * DIN;
        int P = P0 + pos;
        int b = P / LLEN, l = P - b * LLEN;
        size_t base = ((size_t)(b * KDIR) * LLEN + l) * DIN + c;
        size_t pstr = (size_t)LLEN * DIN;
        float v = b2f(ysm[base]) + b2f(ysm[base + pstr]) +
                  b2f(ysm[base + 2 * pstr]) + b2f(ysm[base + 3 * pstr]);
        rb[q] = v;
    }
    __syncthreads();
    {
        int pos = t >> 4, part = t & 15;
        float s = 0.f, s2 = 0.f;
        for (int i = 0; i < 12; ++i) {
            float v = rb[pos * DIN + part * 12 + i];
            s += v; s2 += v * v;
        }
        ps[pos * 16 + part] = s; pq[pos * 16 + part] = s2;
    }
    __syncthreads();
    if (t < 16) {
        float s = 0.f, s2 = 0.f;
        for (int i = 0; i < 16; ++i) { s += ps[t * 16 + i]; s2 += pq[t * 16 + i]; }
        float m = s * (1.f / DIN);
        float v = s2 * (1.f / DIN) - m * m;
        mrow[t] = m; srow[t] = rsqrtf(v + 1e-5f);
    }
    __syncthreads();
    for (int q = t; q < 16 * DIN; q += 256) {
        int pos = q / DIN, c = q - pos * DIN;
        int P = P0 + pos;
        float v = (rb[q] - mrow[pos]) * srow[pos] * onw[c] + onb[c];
        float zv = b2f(z[(size_t)P * DIN + c]);
        v *= zv * sigm(zv);
        ymod[(size_t)P * DIN + c] = f2b(v);
    }
}

// ---- K7: out_proj (192 -> 96) + residual x ---------------------------------
__global__ __launch_bounds__(256) void k7_outproj(
    const bf16* __restrict__ ymod, const float* __restrict__ Wo,
    const float* __restrict__ xin, float* __restrict__ y1) {
    __shared__ float xt[96 * 68];
    __shared__ float wt[96 * 65];
    const int t = threadIdx.x;
    const int P0 = blockIdx.x * 64;
    const int lane = t & 63, wv = t >> 6, jj = lane & 31, ph = lane >> 5;
    const int prow = wv * 16 + ph * 8;
    for (int jt = 0; jt < 2; ++jt) {
        int j0 = jt * 64;
        int jcnt = (96 - j0 < 64) ? (96 - j0) : 64;
        float a0[8] = {0,0,0,0,0,0,0,0}, a1[8] = {0,0,0,0,0,0,0,0};
        for (int cc = 0; cc < 2; ++cc) {
            __syncthreads();
            for (int q = t; q < 64 * 96; q += 256) {
                int pos = q / 96, c = q - pos * 96;
                xt[c * 68 + pos] = b2f(ymod[(size_t)(P0 + pos) * DIN + cc * 96 + c]);
            }
            for (int q = t; q < jcnt * 96; q += 256) {
                int j = q / 96, c = q - j * 96;
                wt[c * 65 + j] = Wo[(size_t)(j0 + j) * DIN + cc * 96 + c];
            }
            __syncthreads();
            gemm_tile_accum(xt, wt, jj, prow, a0, a1);
        }
        for (int m = 0; m < 2; ++m) {
            int j = j0 + jj + 32 * m;
            if (j >= 96) continue;
            const float* ac = m ? a1 : a0;
#pragma unroll
            for (int i = 0; i < 8; ++i) {
                size_t P = (size_t)(P0 + prow + i);
                y1[P * CCH + j] = xin[P * CCH + j] + ac[i];
            }
        }
        __syncthreads();
    }
}

// ---- K8: LN2 + fc1 (96 -> 384) + gelu --------------------------------------
__global__ __launch_bounds__(256) void k8_mlp1(
    const float* __restrict__ y1, const float* __restrict__ lnw,
    const float* __restrict__ lnb, const float* __restrict__ W1,
    const float* __restrict__ b1, bf16* __restrict__ hmlp) {
    __shared__ float xt[96 * 68];
    __shared__ float wt[96 * 65];
    __shared__ float ps[256], pq[256];
    __shared__ float mrow[64], srow[64];
    const int t = threadIdx.x;
    const int P0 = blockIdx.x * 64;
    for (int q = t; q < 64 * 96; q += 256) {
        int pos = q / 96, c = q - pos * 96;
        xt[c * 68 + pos] = y1[(size_t)P0 * 96 + q];
    }
    __syncthreads();
    {
        int pos = t & 63, part = t >> 6;
        float s = 0.f, s2 = 0.f;
        for (int i = 0; i < 24; ++i) {
            float v = xt[(part * 24 + i) * 68 + pos];
            s += v; s2 += v * v;
        }
        ps[part * 64 + pos] = s; pq[part * 64 + pos] = s2;
    }
    __syncthreads();
    if (t < 64) {
        float s = ps[t] + ps[64 + t] + ps[128 + t] + ps[192 + t];
        float s2 = pq[t] + pq[64 + t] + pq[128 + t] + pq[192 + t];
        float m = s * (1.f / 96.f);
        float v = s2 * (1.f / 96.f) - m * m;
        mrow[t] = m; srow[t] = rsqrtf(v + 1e-5f);
    }
    __syncthreads();
    for (int q = t; q < 64 * 96; q += 256) {
        int pos = q / 96, c = q - pos * 96;
        float v = xt[c * 68 + pos];
        xt[c * 68 + pos] = (v - mrow[pos]) * srow[pos] * lnw[c] + lnb[c];
    }
    const int lane = t & 63, wv = t >> 6, jj = lane & 31, ph = lane >> 5;
    const int prow = wv * 16 + ph * 8;
    for (int jt = 0; jt < 6; ++jt) {
        __syncthreads();
        for (int q = t; q < 64 * 96; q += 256) {
            int j = q / 96, c = q - j * 96;
            wt[c * 65 + j] = W1[(size_t)(jt * 64 + j) * 96 + c];
        }
        __syncthreads();
        float a0[8] = {0,0,0,0,0,0,0,0}, a1[8] = {0,0,0,0,0,0,0,0};
        gemm_tile_accum(xt, wt, jj, prow, a0, a1);
        for (int m = 0; m < 2; ++m) {
            int j = jt * 64 + jj + 32 * m;
            const float* ac = m ? a1 : a0;
            float bj = b1[j];
#pragma unroll
            for (int i = 0; i < 8; ++i) {
                int P = P0 + prow + i;
                hmlp[(size_t)P * MLPH + j] = f2b(geluf(ac[i] + bj));
            }
        }
    }
}

// ---- K9: fc2 (384 -> 96) + bias + residual -> out --------------------------
__global__ __launch_bounds__(256) void k9_mlp2(
    const bf16* __restrict__ hmlp, const float* __restrict__ W2,
    const float* __restrict__ b2, const float* __restrict__ y1,
    float* __restrict__ out) {
    __shared__ float xt[96 * 68];
    __shared__ float wt[96 * 65];
    const int t = threadIdx.x;
    const int P0 = blockIdx.x * 64;
    const int lane = t & 63, wv = t >> 6, jj = lane & 31, ph = lane >> 5;
    const int prow = wv * 16 + ph * 8;
    for (int jt = 0; jt < 2; ++jt) {
        int j0 = jt * 64;
        int jcnt = (96 - j0 < 64) ? (96 - j0) : 64;
        float a0[8] = {0,0,0,0,0,0,0,0}, a1[8] = {0,0,0,0,0,0,0,0};
        for (int cc = 0; cc < 4; ++cc) {
            __syncthreads();
            for (int q = t; q < 64 * 96; q += 256) {
                int pos = q / 96, c = q - pos * 96;
                xt[c * 68 + pos] = b2f(hmlp[(size_t)(P0 + pos) * MLPH + cc * 96 + c]);
            }
            for (int q = t; q < jcnt * 96; q += 256) {
                int j = q / 96, c = q - j * 96;
                wt[c * 65 + j] = W2[(size_t)(j0 + j) * MLPH + cc * 96 + c];
            }
            __syncthreads();
            gemm_tile_accum(xt, wt, jj, prow, a0, a1);
        }
        for (int m = 0; m < 2; ++m) {
            int j = j0 + jj + 32 * m;
            if (j >= 96) continue;
            const float* ac = m ? a1 : a0;
            float bj = b2[j];
#pragma unroll
            for (int i = 0; i < 8; ++i) {
                size_t P = (size_t)(P0 + prow + i);
                out[P * CCH + j] = y1[P * CCH + j] + bj + ac[i];
            }
        }
        __syncthreads();
    }
}

extern "C" void kernel_launch(void* const* d_in, const int* in_sizes, int n_in,
                              void* d_out, int out_size, void* d_ws, size_t ws_size,
                              hipStream_t stream) {
    const float* x      = (const float*)d_in[0];
    const float* ln1w   = (const float*)d_in[1];
    const float* ln1b   = (const float*)d_in[2];
    const float* inpW   = (const float*)d_in[3];
    const float* convW  = (const float*)d_in[4];
    const float* convB  = (const float*)d_in[5];
    const float* xprojW = (const float*)d_in[6];
    const float* dtW    = (const float*)d_in[7];
    const float* dtB    = (const float*)d_in[8];
    const float* Alog   = (const float*)d_in[9];
    const float* Dsp    = (const float*)d_in[10];
    const float* onw    = (const float*)d_in[11];
    const float* onb    = (const float*)d_in[12];
    const float* outW   = (const float*)d_in[13];
    const float* ln2w   = (const float*)d_in[14];
    const float* ln2b   = (const float*)d_in[15];
    const float* fc1W   = (const float*)d_in[16];
    const float* fc1b   = (const float*)d_in[17];
    const float* fc2W   = (const float*)d_in[18];
    const float* fc2b   = (const float*)d_in[19];
    float* out = (float*)d_out;

    char* ws = (char*)d_ws;
    bf16*  z_bf     = (bf16*)(ws + 0);              //  9,633,792
    bf16*  xcpre_bf = (bf16*)(ws + 9633792);        //  9,633,792 (dead after k2)
    float* tsum_f   = (float*)(ws + 9633792);       //  aliases xcpre: 1,572,864
    bf16*  xconv_bf = (bf16*)(ws + 19267584);       //  9,633,792
    float* proj_f   = (float*)(ws + 28901376);      // 15,253,504
    float* hloc_f   = (float*)(ws + 44154880);      // 25,165,824
    float* hin_f    = hloc_f;                       //  aliases hloc (k5 r-b-w)
    bf16*  ysm_bf   = (bf16*)(ws + 69320704);       // 38,535,168
    bf16*  hmlp_bf  = (bf16*)(ws + 69320704);       //  aliases ysm (dead after k65)
    bf16*  ymod_bf  = (bf16*)(ws + 107855872);      //  9,633,792
    float* y1_f     = (float*)(ws + 117489664);     //  9,633,792 (end 127,123,456)

    k1_ln_inproj<<<392, 256, 0, stream>>>(x, ln1w, ln1b, inpW, xcpre_bf, z_bf);
    k2_conv<<<18816, 256, 0, stream>>>(xcpre_bf, convW, convB, xconv_bf);
    k3_xproj<<<392, 256, 0, stream>>>(xconv_bf, xprojW, proj_f);
    k4_scan1<<<2048, 192, 0, stream>>>(xconv_bf, proj_f, dtW, dtB, Alog, hloc_f, tsum_f);
    k5_carry<<<768, 256, 0, stream>>>(hloc_f, tsum_f, Alog, hin_f);
    k6_scan2<<<2048, 192, 0, stream>>>(xconv_bf, proj_f, dtW, dtB, Alog, Dsp, hin_f, ysm_bf);
    k65_merge<<<1568, 256, 0, stream>>>(ysm_bf, z_bf, onw, onb, ymod_bf);
    k7_outproj<<<392, 256, 0, stream>>>(ymod_bf, outW, x, y1_f);
    k8_mlp1<<<392, 256, 0, stream>>>(y1_f, ln2w, ln2b, fc1W, fc1b, hmlp_bf);
    k9_mlp2<<<392, 256, 0, stream>>>(hmlp_bf, fc2W, fc2b, y1_f, out);
}

// Round 3
// 417.292 us; speedup vs baseline: 1.8665x; 1.4712x over previous
//
#include <hip/hip_runtime.h>
#include <hip/hip_bf16.h>

typedef __hip_bfloat16 bf16;
typedef short bf16x8 __attribute__((ext_vector_type(8)));
typedef float f32x4 __attribute__((ext_vector_type(4)));

#define BBATCH 8
#define HHH 56
#define WWW 56
#define CCH 96          // C
#define DIN 192         // D
#define NST 16          // N
#define KDIR 4          // K
#define RDT 6           // R
#define LLEN 3136       // H*W
#define BLTOT 25088     // B*L
#define SSEG 64         // segments
#define SEGL 49         // L / SSEG
#define PJC 38          // R + 2N
#define PJW 152         // K * PJC
#define PJS 40          // padded LDS row stride (16B aligned)
#define PJS1 24         // pass-1 padded row stride (r+B only)
#define MLPH 384

__device__ __forceinline__ float b2f(bf16 v) { return __bfloat162float(v); }
__device__ __forceinline__ bf16  f2b(float v) { return __float2bfloat16(v); }
__device__ __forceinline__ unsigned short f2bu(float f) {
    union { bf16 h; unsigned short u; } c; c.h = __float2bfloat16(f); return c.u;
}
__device__ __forceinline__ float sigm(float x) { return 1.f / (1.f + __expf(-x)); }
__device__ __forceinline__ float softplusf(float x) {
    return fmaxf(x, 0.f) + __logf(1.f + __expf(-fabsf(x)));
}
__device__ __forceinline__ float geluf(float v) {
    float u = 0.7978845608028654f * (v + 0.044715f * v * v * v);
    float ey = __expf(2.f * u);
    float th = 1.f - 2.f / (ey + 1.f);
    return 0.5f * v * (1.f + th);
}

// scan-step l -> spatial position (row-major h*56+w) for direction k
__device__ __forceinline__ int pos_map(int k, int l) {
    if (k & 2) l = LLEN - 1 - l;
    if (k & 1) { int q = l / WWW; int r = l - q * WWW; return r * WWW + q; }
    return l;
}

// ---- LN: one wave per row of 96, emit bf16 ---------------------------------
__global__ __launch_bounds__(256) void ln_rows(
    const float* __restrict__ xin, const float* __restrict__ w,
    const float* __restrict__ b, unsigned short* __restrict__ xn) {
    int row = blockIdx.x * 4 + (threadIdx.x >> 6);
    int lane = threadIdx.x & 63;
    const float* xr = xin + (size_t)row * 96;
    float2 v = make_float2(0.f, 0.f);
    if (lane < 48) v = *(const float2*)&xr[lane * 2];
    float s = v.x + v.y, s2 = v.x * v.x + v.y * v.y;
    for (int o = 32; o; o >>= 1) {
        s += __shfl_down(s, o);
        s2 += __shfl_down(s2, o);
    }
    s = __shfl(s, 0); s2 = __shfl(s2, 0);
    float m = s * (1.f / 96.f);
    float var = s2 * (1.f / 96.f) - m * m;
    float rs = rsqrtf(var + 1e-5f);
    if (lane < 48) {
        float o0 = (v.x - m) * rs * w[lane * 2] + b[lane * 2];
        float o1 = (v.y - m) * rs * w[lane * 2 + 1] + b[lane * 2 + 1];
        ushort2 u; u.x = f2bu(o0); u.y = f2bu(o1);
        *(ushort2*)&xn[(size_t)row * 96 + lane * 2] = u;
    }
}

// ---- Unified MFMA GEMM: C[M=25088][N] = X[M][K](bf16) . W[N][K]^T(f32) -----
// block: 4 waves, each wave one 64-row M-strip, 4x4 frags -> 256M x 64N tile.
// EPI: 0=split xc/z  1=proj f32  2=+res f32  3=gelu(+bias) bf16  4=+bias+res f32
template<int N, int K, int EPI>
__global__ __launch_bounds__(256) void gemm_mfma(
    const unsigned short* __restrict__ X, const float* __restrict__ W,
    const float* __restrict__ bias, const float* __restrict__ res,
    void* __restrict__ out0v, void* __restrict__ out1v) {
    __shared__ unsigned short a_sh[256 * 40];
    __shared__ unsigned short b_sh[64 * 40];
    const int t = threadIdx.x;
    const int P0 = blockIdx.x * 256;
    const int N0 = blockIdx.y * 64;
    const int w = t >> 6, lane = t & 63, q = lane >> 4, nl = lane & 15;
    f32x4 acc[4][4];
#pragma unroll
    for (int i = 0; i < 4; ++i)
#pragma unroll
        for (int j = 0; j < 4; ++j)
            acc[i][j] = (f32x4){0.f, 0.f, 0.f, 0.f};
    for (int k0 = 0; k0 < K; k0 += 32) {
        __syncthreads();
        // stage A: 256 rows x 32 k (bf16 pass-through), 16 B per thread-iter
#pragma unroll
        for (int it = 0; it < 4; ++it) {
            int idx = t + it * 256;
            int pr = idx >> 2, kq = idx & 3;
            uint4 v = *(const uint4*)&X[(size_t)(P0 + pr) * K + k0 + kq * 8];
            *(uint4*)&a_sh[pr * 40 + kq * 8] = v;
        }
        // stage B: 64 rows x 32 k, f32 -> bf16
#pragma unroll
        for (int it = 0; it < 2; ++it) {
            int idx = t + it * 256;
            int nr = idx >> 3, kq = idx & 7;
            int ng = N0 + nr; if (ng > N - 1) ng = N - 1;
            float4 v = *(const float4*)&W[(size_t)ng * K + k0 + kq * 4];
            ushort4 u;
            u.x = f2bu(v.x); u.y = f2bu(v.y); u.z = f2bu(v.z); u.w = f2bu(v.w);
            *(ushort4*)&b_sh[nr * 40 + kq * 4] = u;
        }
        __syncthreads();
        bf16x8 af[4], bfr[4];
#pragma unroll
        for (int mf = 0; mf < 4; ++mf)
            af[mf] = *(const bf16x8*)&a_sh[(w * 64 + mf * 16 + nl) * 40 + q * 8];
#pragma unroll
        for (int nf = 0; nf < 4; ++nf)
            bfr[nf] = *(const bf16x8*)&b_sh[(nf * 16 + nl) * 40 + q * 8];
#pragma unroll
        for (int mf = 0; mf < 4; ++mf)
#pragma unroll
            for (int nf = 0; nf < 4; ++nf)
                acc[mf][nf] = __builtin_amdgcn_mfma_f32_16x16x32_bf16(
                    af[mf], bfr[nf], acc[mf][nf], 0, 0, 0);
    }
#pragma unroll
    for (int mf = 0; mf < 4; ++mf) {
#pragma unroll
        for (int nf = 0; nf < 4; ++nf) {
#pragma unroll
            for (int r = 0; r < 4; ++r) {
                float v = acc[mf][nf][r];
                size_t pos = (size_t)P0 + w * 64 + mf * 16 + q * 4 + r;
                int n = N0 + nf * 16 + nl;
                if constexpr (EPI == 0) {
                    unsigned short* xc = (unsigned short*)out0v;
                    unsigned short* zz = (unsigned short*)out1v;
                    if (n < 192) xc[pos * 192 + n] = f2bu(v);
                    else         zz[pos * 192 + (n - 192)] = f2bu(v);
                } else if constexpr (EPI == 1) {
                    if (n < 152) ((float*)out0v)[pos * 152 + n] = v;
                } else if constexpr (EPI == 2) {
                    if (n < 96) ((float*)out0v)[pos * 96 + n] = res[pos * 96 + n] + v;
                } else if constexpr (EPI == 3) {
                    ((unsigned short*)out0v)[pos * 384 + n] = f2bu(geluf(v + bias[n]));
                } else {
                    if (n < 96) ((float*)out0v)[pos * 96 + n] =
                        res[pos * 96 + n] + bias[n] + v;
                }
            }
        }
    }
}

// ---- K2: depthwise 3x3 conv + bias + silu ----------------------------------
__global__ __launch_bounds__(256) void k2_conv(
    const bf16* __restrict__ xcpre, const float* __restrict__ cw,
    const float* __restrict__ cb, bf16* __restrict__ xconv) {
    int idx = blockIdx.x * 256 + threadIdx.x;
    int d = idx % DIN;
    int P = idx / DIN;
    int b = P / LLEN, l = P - b * LLEN;
    int h = l / WWW, w = l - h * WWW;
    float acc = cb[d];
#pragma unroll
    for (int i = 0; i < 3; ++i) {
        int hh = h + i - 1;
        if (hh < 0 || hh >= HHH) continue;
#pragma unroll
        for (int j = 0; j < 3; ++j) {
            int ww = w + j - 1;
            if (ww < 0 || ww >= WWW) continue;
            float xv = b2f(xcpre[((size_t)(b * LLEN + hh * WWW + ww)) * DIN + d]);
            acc = fmaf(xv, cw[d * 9 + i * 3 + j], acc);
        }
    }
    acc = acc * sigm(acc);
    xconv[(size_t)P * DIN + d] = f2b(acc);
}

// ---- K4: scan pass 1 — per-segment local h_end and sum(dt) -----------------
__global__ __launch_bounds__(192) void k4_scan1(
    const bf16* __restrict__ xconv, const float* __restrict__ proj,
    const float* __restrict__ dtw, const float* __restrict__ dtb,
    const float* __restrict__ Alog, float* __restrict__ hloc,
    float* __restrict__ tsum) {
    __shared__ float pl[SEGL * PJS1];
    __shared__ int posl[SEGL];
    const int bid = blockIdx.x;
    const int s = bid & 63, k = (bid >> 6) & 3, b = bid >> 8;
    const int d = threadIdx.x;
    const int l0 = s * SEGL;
    for (int q = d; q < SEGL * 22; q += 192) {
        int st = q / 22, c = q - st * 22;
        int p = pos_map(k, l0 + st);
        int ofs = (c < 6) ? c : c + 2;
        pl[st * PJS1 + ofs] = proj[(size_t)(b * LLEN + p) * PJW + k * PJC + c];
    }
    if (d < SEGL) posl[d] = pos_map(k, l0 + d) * DIN;
    float w6[RDT];
#pragma unroll
    for (int r = 0; r < RDT; ++r) w6[r] = dtw[(k * DIN + d) * RDT + r];
    const float bias = dtb[k * DIN + d];
    float a[NST];
#pragma unroll
    for (int n = 0; n < NST; ++n) a[n] = -__expf(Alog[(k * DIN + d) * NST + n]);
    float h[NST];
#pragma unroll
    for (int n = 0; n < NST; ++n) h[n] = 0.f;
    float T = 0.f;
    __syncthreads();
    const bf16* xg = xconv + (size_t)b * LLEN * DIN + d;
    for (int bt = 0; bt < 7; ++bt) {
        int off7[7]; float xv7[7];
#pragma unroll
        for (int i = 0; i < 7; ++i) off7[i] = posl[bt * 7 + i];
#pragma unroll
        for (int i = 0; i < 7; ++i) xv7[i] = b2f(xg[off7[i]]);
#pragma unroll
        for (int i = 0; i < 7; ++i) {
            const float* rowf = &pl[(bt * 7 + i) * PJS1];
            float4 g0 = *(const float4*)(rowf);
            float2 g1 = *(const float2*)(rowf + 4);
            float dtv = bias;
            dtv = fmaf(g0.x, w6[0], dtv); dtv = fmaf(g0.y, w6[1], dtv);
            dtv = fmaf(g0.z, w6[2], dtv); dtv = fmaf(g0.w, w6[3], dtv);
            dtv = fmaf(g1.x, w6[4], dtv); dtv = fmaf(g1.y, w6[5], dtv);
            dtv = softplusf(dtv);
            T += dtv;
            float u = dtv * xv7[i];
#pragma unroll
            for (int g = 0; g < 4; ++g) {
                float4 Bv = *(const float4*)(rowf + 8 + 4 * g);
                float e0 = __expf(dtv * a[4 * g + 0]);
                float e1 = __expf(dtv * a[4 * g + 1]);
                float e2 = __expf(dtv * a[4 * g + 2]);
                float e3 = __expf(dtv * a[4 * g + 3]);
                h[4 * g + 0] = fmaf(h[4 * g + 0], e0, u * Bv.x);
                h[4 * g + 1] = fmaf(h[4 * g + 1], e1, u * Bv.y);
                h[4 * g + 2] = fmaf(h[4 * g + 2], e2, u * Bv.z);
                h[4 * g + 3] = fmaf(h[4 * g + 3], e3, u * Bv.w);
            }
        }
    }
    size_t base = ((size_t)bid * DIN + d) * NST;
#pragma unroll
    for (int n = 0; n < NST; ++n) hloc[base + n] = h[n];
    tsum[bid * DIN + d] = T;
}

// ---- K5: exact segment carries (hin aliases hloc: read-before-write) -------
__global__ __launch_bounds__(256) void k5_carry(
    const float* hloc, const float* __restrict__ tsum,
    const float* __restrict__ Alog, float* hin) {
    int g = blockIdx.x * 256 + threadIdx.x;   // over B*K*D*N
    int n = g & 15;
    int dk = g >> 4;
    int d = dk % DIN;
    int bk = dk / DIN;                        // b*4 + k
    int k = bk & 3;
    float a = -__expf(Alog[(k * DIN + d) * NST + n]);
    float Hc = 0.f;
    for (int s = 0; s < SSEG; ++s) {
        int bid = bk * SSEG + s;
        size_t idx = ((size_t)bid * DIN + d) * NST + n;
        float hl = hloc[idx];
        float Tv = tsum[bid * DIN + d];
        hin[idx] = Hc;
        Hc = fmaf(__expf(a * Tv), Hc, hl);
    }
}

// ---- K6: scan pass 2 — exact scan from carries, emit y (merged pos) --------
__global__ __launch_bounds__(192) void k6_scan2(
    const bf16* __restrict__ xconv, const float* __restrict__ proj,
    const float* __restrict__ dtw, const float* __restrict__ dtb,
    const float* __restrict__ Alog, const float* __restrict__ Dsp,
    const float* __restrict__ hin, bf16* __restrict__ ysm) {
    __shared__ float pl[SEGL * PJS];
    __shared__ int posl[SEGL];
    const int bid = blockIdx.x;
    const int s = bid & 63, k = (bid >> 6) & 3, b = bid >> 8;
    const int d = threadIdx.x;
    const int l0 = s * SEGL;
    for (int q = d; q < SEGL * PJC; q += 192) {
        int st = q / PJC, c = q - st * PJC;
        int p = pos_map(k, l0 + st);
        int ofs = (c < 6) ? c : c + 2;
        pl[st * PJS + ofs] = proj[(size_t)(b * LLEN + p) * PJW + k * PJC + c];
    }
    if (d < SEGL) posl[d] = pos_map(k, l0 + d) * DIN;
    float w6[RDT];
#pragma unroll
    for (int r = 0; r < RDT; ++r) w6[r] = dtw[(k * DIN + d) * RDT + r];
    const float bias = dtb[k * DIN + d];
    const float dsv = Dsp[k * DIN + d];
    float a[NST];
#pragma unroll
    for (int n = 0; n < NST; ++n) a[n] = -__expf(Alog[(k * DIN + d) * NST + n]);
    float h[NST];
    size_t hbase = ((size_t)bid * DIN + d) * NST;
#pragma unroll
    for (int n = 0; n < NST; ++n) h[n] = hin[hbase + n];
    __syncthreads();
    const bf16* xg = xconv + (size_t)b * LLEN * DIN + d;
    bf16* ysg = ysm + ((size_t)(b * KDIR + k) * LLEN) * DIN + d;
    for (int bt = 0; bt < 7; ++bt) {
        int off7[7]; float xv7[7];
#pragma unroll
        for (int i = 0; i < 7; ++i) off7[i] = posl[bt * 7 + i];
#pragma unroll
        for (int i = 0; i < 7; ++i) xv7[i] = b2f(xg[off7[i]]);
#pragma unroll
        for (int i = 0; i < 7; ++i) {
            const float* rowf = &pl[(bt * 7 + i) * PJS];
            float4 g0 = *(const float4*)(rowf);
            float2 g1 = *(const float2*)(rowf + 4);
            float dtv = bias;
            dtv = fmaf(g0.x, w6[0], dtv); dtv = fmaf(g0.y, w6[1], dtv);
            dtv = fmaf(g0.z, w6[2], dtv); dtv = fmaf(g0.w, w6[3], dtv);
            dtv = fmaf(g1.x, w6[4], dtv); dtv = fmaf(g1.y, w6[5], dtv);
            dtv = softplusf(dtv);
            float u = dtv * xv7[i];
            float y = dsv * xv7[i];
#pragma unroll
            for (int g = 0; g < 4; ++g) {
                float4 Bv = *(const float4*)(rowf + 8 + 4 * g);
                float4 Cv = *(const float4*)(rowf + 24 + 4 * g);
                float e0 = __expf(dtv * a[4 * g + 0]);
                float e1 = __expf(dtv * a[4 * g + 1]);
                float e2 = __expf(dtv * a[4 * g + 2]);
                float e3 = __expf(dtv * a[4 * g + 3]);
                h[4 * g + 0] = fmaf(h[4 * g + 0], e0, u * Bv.x);
                h[4 * g + 1] = fmaf(h[4 * g + 1], e1, u * Bv.y);
                h[4 * g + 2] = fmaf(h[4 * g + 2], e2, u * Bv.z);
                h[4 * g + 3] = fmaf(h[4 * g + 3], e3, u * Bv.w);
                y = fmaf(h[4 * g + 0], Cv.x, y);
                y = fmaf(h[4 * g + 1], Cv.y, y);
                y = fmaf(h[4 * g + 2], Cv.z, y);
                y = fmaf(h[4 * g + 3], Cv.w, y);
            }
            ysg[off7[i]] = f2b(y);
        }
    }
}

// ---- K6.5: merge 4 planes + out_norm LN + *silu(z) -------------------------
__global__ __launch_bounds__(256) void k65_merge(
    const bf16* __restrict__ ysm, const bf16* __restrict__ z,
    const float* __restrict__ onw, const float* __restrict__ onb,
    bf16* __restrict__ ymod) {
    __shared__ float rb[16 * DIN];
    __shared__ float ps[256], pq[256];
    __shared__ float mrow[16], srow[16];
    const int t = threadIdx.x;
    const int P0 = blockIdx.x * 16;
    for (int q = t; q < 16 * DIN; q += 256) {
        int pos = q / DIN, c = q - pos * DIN;
        int P = P0 + pos;
        int b = P / LLEN, l = P - b * LLEN;
        size_t base = ((size_t)(b * KDIR) * LLEN + l) * DIN + c;
        size_t pstr = (size_t)LLEN * DIN;
        float v = b2f(ysm[base]) + b2f(ysm[base + pstr]) +
                  b2f(ysm[base + 2 * pstr]) + b2f(ysm[base + 3 * pstr]);
        rb[q] = v;
    }
    __syncthreads();
    {
        int pos = t >> 4, part = t & 15;
        float s = 0.f, s2 = 0.f;
        for (int i = 0; i < 12; ++i) {
            float v = rb[pos * DIN + part * 12 + i];
            s += v; s2 += v * v;
        }
        ps[pos * 16 + part] = s; pq[pos * 16 + part] = s2;
    }
    __syncthreads();
    if (t < 16) {
        float s = 0.f, s2 = 0.f;
        for (int i = 0; i < 16; ++i) { s += ps[t * 16 + i]; s2 += pq[t * 16 + i]; }
        float m = s * (1.f / DIN);
        float v = s2 * (1.f / DIN) - m * m;
        mrow[t] = m; srow[t] = rsqrtf(v + 1e-5f);
    }
    __syncthreads();
    for (int q = t; q < 16 * DIN; q += 256) {
        int pos = q / DIN, c = q - pos * DIN;
        int P = P0 + pos;
        float v = (rb[q] - mrow[pos]) * srow[pos] * onw[c] + onb[c];
        float zv = b2f(z[(size_t)P * DIN + c]);
        v *= zv * sigm(zv);
        ymod[(size_t)P * DIN + c] = f2b(v);
    }
}

extern "C" void kernel_launch(void* const* d_in, const int* in_sizes, int n_in,
                              void* d_out, int out_size, void* d_ws, size_t ws_size,
                              hipStream_t stream) {
    const float* x      = (const float*)d_in[0];
    const float* ln1w   = (const float*)d_in[1];
    const float* ln1b   = (const float*)d_in[2];
    const float* inpW   = (const float*)d_in[3];
    const float* convW  = (const float*)d_in[4];
    const float* convB  = (const float*)d_in[5];
    const float* xprojW = (const float*)d_in[6];
    const float* dtW    = (const float*)d_in[7];
    const float* dtB    = (const float*)d_in[8];
    const float* Alog   = (const float*)d_in[9];
    const float* Dsp    = (const float*)d_in[10];
    const float* onw    = (const float*)d_in[11];
    const float* onb    = (const float*)d_in[12];
    const float* outW   = (const float*)d_in[13];
    const float* ln2w   = (const float*)d_in[14];
    const float* ln2b   = (const float*)d_in[15];
    const float* fc1W   = (const float*)d_in[16];
    const float* fc1b   = (const float*)d_in[17];
    const float* fc2W   = (const float*)d_in[18];
    const float* fc2b   = (const float*)d_in[19];
    float* out = (float*)d_out;

    char* ws = (char*)d_ws;
    // region map (offsets in bytes, lifetimes commented):
    unsigned short* z_us    = (unsigned short*)(ws + 0);           // [G1..k65]  9,633,792
    bf16*  z_bf             = (bf16*)z_us;
    bf16*  xconv_bf         = (bf16*)(ws + 9633792);               // [k2..k6]   9,633,792
    float* proj_f           = (float*)(ws + 19267584);             // [G2..k6]  15,253,504
    bf16*  ymod_bf          = (bf16*)(ws + 19267584);              // [k65..G3] aliases proj
    unsigned short* xn_us   = (unsigned short*)(ws + 34521088);    // [LN1..G1]  4,816,896
    float* tsum_f           = (float*)(ws + 34521088);             // [k4..k6]  aliases xn
    unsigned short* xcpre_us= (unsigned short*)(ws + 39337984);    // [G1..k2]   9,633,792
    bf16*  xcpre_bf         = (bf16*)xcpre_us;
    float* hloc_f           = (float*)(ws + 48971776);             // [k4..k6]  25,165,824
    float* hin_f            = hloc_f;                              // k5 r-b-w alias
    float* y1_f             = (float*)(ws + 48971776);             // [G3..G5]  aliases hloc
    unsigned short* y1n_us  = (unsigned short*)(ws + 58605568);    // [LN2..G4]  4,816,896
    bf16*  ysm_bf           = (bf16*)(ws + 74137600);              // [k6..k65] 38,535,168
    unsigned short* hmlp_us = (unsigned short*)(ws + 74137600);    // [G4..G5]  aliases ysm
    // end of live map: 112,672,768 bytes

    ln_rows<<<6272, 256, 0, stream>>>(x, ln1w, ln1b, xn_us);
    gemm_mfma<384, 96, 0><<<dim3(98, 6), 256, 0, stream>>>(
        xn_us, inpW, nullptr, nullptr, xcpre_us, z_us);
    k2_conv<<<18816, 256, 0, stream>>>(xcpre_bf, convW, convB, xconv_bf);
    gemm_mfma<152, 192, 1><<<dim3(98, 3), 256, 0, stream>>>(
        (const unsigned short*)xconv_bf, xprojW, nullptr, nullptr, proj_f, nullptr);
    k4_scan1<<<2048, 192, 0, stream>>>(xconv_bf, proj_f, dtW, dtB, Alog, hloc_f, tsum_f);
    k5_carry<<<384, 256, 0, stream>>>(hloc_f, tsum_f, Alog, hin_f);
    k6_scan2<<<2048, 192, 0, stream>>>(xconv_bf, proj_f, dtW, dtB, Alog, Dsp, hin_f, ysm_bf);
    k65_merge<<<1568, 256, 0, stream>>>(ysm_bf, z_bf, onw, onb, ymod_bf);
    gemm_mfma<96, 192, 2><<<dim3(98, 2), 256, 0, stream>>>(
        (const unsigned short*)ymod_bf, outW, nullptr, x, y1_f, nullptr);
    ln_rows<<<6272, 256, 0, stream>>>(y1_f, ln2w, ln2b, y1n_us);
    gemm_mfma<384, 96, 3><<<dim3(98, 6), 256, 0, stream>>>(
        y1n_us, fc1W, fc1b, nullptr, hmlp_us, nullptr);
    gemm_mfma<96, 384, 4><<<dim3(98, 2), 256, 0, stream>>>(
        hmlp_us, fc2W, fc2b, y1_f, out, nullptr);
}